// Round 3
// baseline (70.384 us; speedup 1.0000x reference)
//
#include <hip/hip_runtime.h>

typedef float    f32x4 __attribute__((ext_vector_type(4)));
typedef _Float16 f16x8 __attribute__((ext_vector_type(8)));
typedef _Float16 f16x4 __attribute__((ext_vector_type(4)));

#define MFMA16 __builtin_amdgcn_mfma_f32_16x16x32_f16

#define NQ     400
#define DMODEL 768

// mask-before-scale folded with log2e for exp2:
// ref: softmax((S - (1-mq*mk)*1e5)/8); e^z = 2^(z*log2e)
#define SCL 0.18033688011112042f   /* 0.125 * log2(e) */
#define PEN 18033.688011112043f    /* 12500 * log2(e) */

// LDS layout (bytes)
#define K_OFF    0                  // K fp16 [400][64], 128B rows, XOR-swizzled by (row&7)<<4
#define VT_OFF   51200              // V^T fp16 [64][424], 848B rows, k block-permuted; 54272B
#define W_OFF    105472             // W fp16 x3, [64] rows of 128B, XOR-swizzled; 24576B
#define QS_OFF   130048             // Q transpose scratch, 16 waves x 2048B = 32768B
#define BIAS_OFF 162816             // bias f32 [3][64]
#define MKB_OFF  163584             // mask bits, 16 u32
#define SMEM_BYTES 163648

__device__ __forceinline__ f16x8 cvt8(const float* rp) {
    f32x4 u0 = *(const f32x4*)(rp);
    f32x4 u1 = *(const f32x4*)(rp + 4);
    f16x8 a;
    a[0] = (_Float16)u0[0]; a[1] = (_Float16)u0[1];
    a[2] = (_Float16)u0[2]; a[3] = (_Float16)u0[3];
    a[4] = (_Float16)u1[0]; a[5] = (_Float16)u1[1];
    a[6] = (_Float16)u1[2]; a[7] = (_Float16)u1[3];
    return a;
}

__global__ __launch_bounds__(1024)
void attn_fused(const float* __restrict__ R, const float* __restrict__ Rmas,
                const float* __restrict__ Wq, const float* __restrict__ bq,
                const float* __restrict__ Wk, const float* __restrict__ bk,
                const float* __restrict__ Wv, const float* __restrict__ bv,
                float* __restrict__ out)
{
    extern __shared__ char smem[];
    const int tid  = threadIdx.x;
    const int lane = tid & 63;
    const int wv   = tid >> 6;      // 0..15
    const int g    = lane >> 4;
    const int q16  = lane & 15;
    const int csw  = (q16 & 7) << 4;

    const int blk = blockIdx.x;
    const int b   = blk / 12;
    const int h   = blk % 12;

    // ---------- phase 0: stage W (fp16, swizzled 128B rows), bias, mask bits; zero-pad VT ----------
    {
        if (tid < 768) {
            const int m   = tid >> 8;
            const int idx = tid & 255;
            const int row = idx >> 2;          // 0..63
            const int c0  = (idx & 3) << 4;    // 0,16,32,48
            const float* Wm = (m == 0 ? Wq : (m == 1 ? Wk : Wv)) + row * 64 + c0;
            const int sw = (row & 7) << 4;
            #pragma unroll
            for (int k2 = 0; k2 < 2; ++k2) {
                f32x4 v0 = *(const f32x4*)(Wm + 8 * k2);
                f32x4 v1 = *(const f32x4*)(Wm + 8 * k2 + 4);
                f16x8 hv;
                hv[0]=(_Float16)v0[0]; hv[1]=(_Float16)v0[1];
                hv[2]=(_Float16)v0[2]; hv[3]=(_Float16)v0[3];
                hv[4]=(_Float16)v1[0]; hv[5]=(_Float16)v1[1];
                hv[6]=(_Float16)v1[2]; hv[7]=(_Float16)v1[3];
                *(f16x8*)(smem + W_OFF + m * 8192 + row * 128 + ((c0 * 2 + 16 * k2) ^ sw)) = hv;
            }
        } else if (tid < 960) {
            const int j = tid - 768;
            const float* bms[3] = {bq, bk, bv};
            *(float*)(smem + BIAS_OFF + j * 4) = bms[j >> 6][j & 63];
        }
        if (wv < 7) {
            const int i = (wv << 6) | lane;
            const float mval = (i < NQ) ? Rmas[b * NQ + i] : 0.0f;
            unsigned long long bb = __ballot(mval != 0.0f);
            if (lane == 0) {
                ((unsigned*)(smem + MKB_OFF))[2 * wv]     = (unsigned)bb;
                ((unsigned*)(smem + MKB_OFF))[2 * wv + 1] = (unsigned)(bb >> 32);
            }
        }
        // zero-pad V^T permuted block 12 upper halves (orig k 400..415)
        if (tid < 256) {
            const int r = tid >> 2, c = tid & 3;
            *(f16x4*)(smem + VT_OFF + r * 848 + 768 + c * 16 + 8) = (f16x4){0, 0, 0, 0};
        }
    }
    __syncthreads();

    const float* Rbh = R + (size_t)b * NQ * DMODEL + h * 64;

    // ---------- phase 1: QKV projections; K,V^T -> LDS; own Q tiles -> registers ----------
    f16x8 qreg[2][2];
    const int QSw = QS_OFF + wv * 2048;
    #pragma unroll
    for (int tt = 0; tt < 2; ++tt) {
        const int t = wv + 16 * tt;
        if (t < 25) {
            const float* rp = Rbh + (size_t)(t * 16 + q16) * DMODEL + g * 8;
            f16x8 af0 = cvt8(rp);
            f16x8 af1 = cvt8(rp + 32);
            #pragma unroll
            for (int m = 0; m < 3; ++m) {
                #pragma unroll
                for (int cg = 0; cg < 4; ++cg) {
                    const int col = cg * 16 + q16;
                    const float bb = *(const float*)(smem + BIAS_OFF + (m * 64 + col) * 4);
                    f32x4 acc = {bb, bb, bb, bb};
                    f16x8 wb0 = *(const f16x8*)(smem + W_OFF + m * 8192 + col * 128 + ((g * 16) ^ csw));
                    f16x8 wb1 = *(const f16x8*)(smem + W_OFF + m * 8192 + col * 128 + ((64 + g * 16) ^ csw));
                    acc = MFMA16(af0, wb0, acc, 0, 0, 0);
                    acc = MFMA16(af1, wb1, acc, 0, 0, 0);
                    if (m == 0) {
                        // Q -> wave-private transpose scratch (swizzled 128B rows)
                        #pragma unroll
                        for (int r = 0; r < 4; ++r) {
                            const int rr = 4 * g + r;
                            *(_Float16*)(smem + QSw + rr * 128 + ((col * 2) ^ ((rr & 7) << 4))) =
                                (_Float16)acc[r];
                        }
                    } else if (m == 1) {
                        // K row-major, swizzled
                        #pragma unroll
                        for (int r = 0; r < 4; ++r) {
                            const int kk = t * 16 + 4 * g + r;
                            *(_Float16*)(smem + K_OFF + kk * 128 + ((col * 2) ^ ((kk & 7) << 4))) =
                                (_Float16)acc[r];
                        }
                    } else {
                        // V^T with block-permuted k order: k=16t+4g+{0..3} lands at
                        // byte (t>>1)*64 + g*16 + (t&1)*8 within row `col`
                        f16x4 hv;
                        hv[0]=(_Float16)acc[0]; hv[1]=(_Float16)acc[1];
                        hv[2]=(_Float16)acc[2]; hv[3]=(_Float16)acc[3];
                        *(f16x4*)(smem + VT_OFF + col * 848 + (t >> 1) * 64 + g * 16 + (t & 1) * 8) = hv;
                    }
                }
            }
            asm volatile("s_waitcnt lgkmcnt(0)" ::: "memory");
            qreg[tt][0] = *(const f16x8*)(smem + QSw + q16 * 128 + ((g * 16)      ^ csw));
            qreg[tt][1] = *(const f16x8*)(smem + QSw + q16 * 128 + ((64 + g * 16) ^ csw));
        }
    }
    __syncthreads();

    // ---------- phase 2: attention, P fully register-resident ----------
    unsigned mkw[13];
    #pragma unroll
    for (int i = 0; i < 13; ++i) mkw[i] = ((const unsigned*)(smem + MKB_OFF))[i];

    #pragma unroll
    for (int ti = 0; ti < 2; ++ti) {
        const int qt = wv + 16 * ti;
        if (qt < 25) {
            const int qrow = qt * 16 + q16;
            const unsigned qb = (mkw[qrow >> 5] >> (qrow & 31)) & 1u;

            // swapped QK^T: lane (g,q16) accumulates S[q16][16kt+4g+r]
            f32x4 a[25];
            #pragma unroll
            for (int kt = 0; kt < 25; ++kt) {
                const int krow = kt * 16 + q16;
                f16x8 kf0 = *(const f16x8*)(smem + K_OFF + krow * 128 + ((g * 16)      ^ csw));
                f16x8 kf1 = *(const f16x8*)(smem + K_OFF + krow * 128 + ((64 + g * 16) ^ csw));
                f32x4 acc = {0.f, 0.f, 0.f, 0.f};
                acc = MFMA16(kf0, qreg[ti][0], acc, 0, 0, 0);
                acc = MFMA16(kf1, qreg[ti][1], acc, 0, 0, 0);
                a[kt] = acc;
            }

            // mask (bitmask penalty) + scale, row max (row is lane-local)
            float pm = -3e38f;
            #pragma unroll
            for (int kt = 0; kt < 25; ++kt) {
                const unsigned wsh = mkw[kt >> 1] >> (((kt & 1) << 4) + 4 * g);
                #pragma unroll
                for (int r = 0; r < 4; ++r) {
                    float xx = a[kt][r] * SCL;
                    if (!((wsh >> r) & 1u)) xx -= PEN;
                    a[kt][r] = xx;
                    pm = fmaxf(pm, xx);
                }
            }
            pm = fmaxf(pm, __shfl_xor(pm, 16));
            pm = fmaxf(pm, __shfl_xor(pm, 32));

            // exp2 + row sum; pack P to f16 in registers
            float ps = 0.f;
            f16x4 ph[26];
            #pragma unroll
            for (int kt = 0; kt < 25; ++kt) {
                #pragma unroll
                for (int r = 0; r < 4; ++r) {
                    const float e = __builtin_amdgcn_exp2f(a[kt][r] - pm);
                    ps += e;
                    ph[kt][r] = (_Float16)e;
                }
            }
            ph[25] = (f16x4){0, 0, 0, 0};
            ps += __shfl_xor(ps, 16);
            ps += __shfl_xor(ps, 32);
            const float myrs = qb ? __builtin_amdgcn_rcpf(ps) : 0.0f;

            // PV: P-frag straight from registers (kappa matches permuted VT)
            f32x4 oc[4];
            #pragma unroll
            for (int cg = 0; cg < 4; ++cg) oc[cg] = (f32x4){0.f, 0.f, 0.f, 0.f};
            #pragma unroll
            for (int kc = 0; kc < 13; ++kc) {
                union { f16x4 hh[2]; f16x8 v; } pu;
                pu.hh[0] = ph[2 * kc];
                pu.hh[1] = ph[2 * kc + 1];
                const f16x8 pa = pu.v;
                #pragma unroll
                for (int cg = 0; cg < 4; ++cg) {
                    f16x8 vb = *(const f16x8*)(smem + VT_OFF + (cg * 16 + q16) * 848 + kc * 64 + g * 16);
                    oc[cg] = MFMA16(pa, vb, oc[cg], 0, 0, 0);
                }
            }

            // epilogue: redistribute row-scale via shfl, store fp32
            float rs[4];
            #pragma unroll
            for (int r = 0; r < 4; ++r) rs[r] = __shfl(myrs, 4 * g + r);
            float* op = out + (size_t)(b * NQ + qt * 16) * DMODEL + h * 64;
            #pragma unroll
            for (int r = 0; r < 4; ++r) {
                #pragma unroll
                for (int cg = 0; cg < 4; ++cg)
                    op[(4 * g + r) * DMODEL + cg * 16 + q16] = oc[cg][r] * rs[r];
            }
        }
    }
}

extern "C" void kernel_launch(void* const* d_in, const int* in_sizes, int n_in,
                              void* d_out, int out_size, void* d_ws, size_t ws_size,
                              hipStream_t stream) {
    const float* R    = (const float*)d_in[0];
    const float* Rmas = (const float*)d_in[1];
    const float* Wq   = (const float*)d_in[2];
    const float* bq   = (const float*)d_in[3];
    const float* Wk   = (const float*)d_in[4];
    const float* bk   = (const float*)d_in[5];
    const float* Wv   = (const float*)d_in[6];
    const float* bv   = (const float*)d_in[7];
    float* out = (float*)d_out;

    (void)hipFuncSetAttribute(reinterpret_cast<const void*>(attn_fused),
                              hipFuncAttributeMaxDynamicSharedMemorySize, SMEM_BYTES);
    attn_fused<<<dim3(384), dim3(1024), SMEM_BYTES, stream>>>(R, Rmas, Wq, bq, Wk, bk, Wv, bv, out);
}

// Round 4
// 57.663 us; speedup vs baseline: 1.2206x; 1.2206x over previous
//
#include <hip/hip_runtime.h>

typedef float    f32x4 __attribute__((ext_vector_type(4)));
typedef _Float16 f16x8 __attribute__((ext_vector_type(8)));
typedef _Float16 f16x4 __attribute__((ext_vector_type(4)));

#define MFMA16 __builtin_amdgcn_mfma_f32_16x16x32_f16

#define NQ     400
#define DMODEL 768

// mask-before-scale folded with log2e for exp2:
// ref: softmax((S - (1-mq*mk)*1e5)/8); e^z = 2^(z*log2e)
#define SCL 0.18033688011112042f   /* 0.125 * log2(e) */
#define PEN 18033.688011112043f    /* 12500 * log2(e) */

// LDS layout (bytes)
#define K_OFF    0                  // K fp16 [400][64], 128B rows, XOR-swizzled by (row&7)<<4
#define VT_OFF   51200              // V^T fp16 [64][424], 848B rows, k block-permuted; 54272B
#define W_OFF    105472             // W fp16 x3, [64] rows of 128B, XOR-swizzled; 24576B
#define QS_OFF   130048             // Q transpose scratch, 16 waves x 2048B = 32768B
#define BIAS_OFF 162816             // bias f32 [3][64]
#define MKB_OFF  163584             // mask bits, 16 u32
#define SMEM_BYTES 163648

__device__ __forceinline__ f16x8 cvt8(const float* rp) {
    f32x4 u0 = *(const f32x4*)(rp);
    f32x4 u1 = *(const f32x4*)(rp + 4);
    f16x8 a;
    a[0] = (_Float16)u0[0]; a[1] = (_Float16)u0[1];
    a[2] = (_Float16)u0[2]; a[3] = (_Float16)u0[3];
    a[4] = (_Float16)u1[0]; a[5] = (_Float16)u1[1];
    a[6] = (_Float16)u1[2]; a[7] = (_Float16)u1[3];
    return a;
}

// project one 16-row tile through W_m (m=1:K, m=2:V) and store to LDS
template <int M>
__device__ __forceinline__ void proj_kv(char* smem, f16x8 af0, f16x8 af1,
                                        int t, int g, int q16, int csw) {
    #pragma unroll
    for (int cg = 0; cg < 4; ++cg) {
        const int col = cg * 16 + q16;
        const float bb = *(const float*)(smem + BIAS_OFF + (M * 64 + col) * 4);
        f32x4 acc = {bb, bb, bb, bb};
        f16x8 wb0 = *(const f16x8*)(smem + W_OFF + M * 8192 + col * 128 + ((g * 16) ^ csw));
        f16x8 wb1 = *(const f16x8*)(smem + W_OFF + M * 8192 + col * 128 + ((64 + g * 16) ^ csw));
        acc = MFMA16(af0, wb0, acc, 0, 0, 0);
        acc = MFMA16(af1, wb1, acc, 0, 0, 0);
        if (M == 1) {
            // K row-major, swizzled
            #pragma unroll
            for (int r = 0; r < 4; ++r) {
                const int kk = t * 16 + 4 * g + r;
                *(_Float16*)(smem + K_OFF + kk * 128 + ((col * 2) ^ ((kk & 7) << 4))) =
                    (_Float16)acc[r];
            }
        } else {
            // V^T with block-permuted k order: k=16t+4g+{0..3} lands at
            // byte (t>>1)*64 + g*16 + (t&1)*8 within row `col`
            f16x4 hv;
            hv[0]=(_Float16)acc[0]; hv[1]=(_Float16)acc[1];
            hv[2]=(_Float16)acc[2]; hv[3]=(_Float16)acc[3];
            *(f16x4*)(smem + VT_OFF + col * 848 + (t >> 1) * 64 + g * 16 + (t & 1) * 8) = hv;
        }
    }
}

__global__ __launch_bounds__(1024, 4)
void attn_fused(const float* __restrict__ R, const float* __restrict__ Rmas,
                const float* __restrict__ Wq, const float* __restrict__ bq,
                const float* __restrict__ Wk, const float* __restrict__ bk,
                const float* __restrict__ Wv, const float* __restrict__ bv,
                float* __restrict__ out)
{
    extern __shared__ char smem[];
    const int tid  = threadIdx.x;
    const int lane = tid & 63;
    const int wv   = tid >> 6;      // 0..15
    const int g    = lane >> 4;
    const int q16  = lane & 15;
    const int csw  = (q16 & 7) << 4;

    const int blk  = blockIdx.x;
    const int b    = blk / 24;
    const int rem  = blk - b * 24;
    const int h    = rem >> 1;
    const int half = rem & 1;
    const int qlo   = half ? 13 : 0;
    const int ntile = half ? 12 : 13;

    // ---------- phase 0: stage W (fp16, swizzled 128B rows), bias, mask bits; zero-pad VT ----------
    {
        if (tid < 768) {
            const int m   = tid >> 8;
            const int idx = tid & 255;
            const int row = idx >> 2;          // 0..63
            const int c0  = (idx & 3) << 4;    // 0,16,32,48
            const float* Wm = (m == 0 ? Wq : (m == 1 ? Wk : Wv)) + row * 64 + c0;
            const int sw = (row & 7) << 4;
            #pragma unroll
            for (int k2 = 0; k2 < 2; ++k2) {
                f32x4 v0 = *(const f32x4*)(Wm + 8 * k2);
                f32x4 v1 = *(const f32x4*)(Wm + 8 * k2 + 4);
                f16x8 hv;
                hv[0]=(_Float16)v0[0]; hv[1]=(_Float16)v0[1];
                hv[2]=(_Float16)v0[2]; hv[3]=(_Float16)v0[3];
                hv[4]=(_Float16)v1[0]; hv[5]=(_Float16)v1[1];
                hv[6]=(_Float16)v1[2]; hv[7]=(_Float16)v1[3];
                *(f16x8*)(smem + W_OFF + m * 8192 + row * 128 + ((c0 * 2 + 16 * k2) ^ sw)) = hv;
            }
        } else if (tid < 960) {
            const int j = tid - 768;
            const float* bms[3] = {bq, bk, bv};
            *(float*)(smem + BIAS_OFF + j * 4) = bms[j >> 6][j & 63];
        }
        if (wv < 7) {
            const int i = (wv << 6) | lane;
            const float mval = (i < NQ) ? Rmas[b * NQ + i] : 0.0f;
            unsigned long long bb = __ballot(mval != 0.0f);
            if (lane == 0) {
                ((unsigned*)(smem + MKB_OFF))[2 * wv]     = (unsigned)bb;
                ((unsigned*)(smem + MKB_OFF))[2 * wv + 1] = (unsigned)(bb >> 32);
            }
        }
        // zero-pad V^T permuted block 12 upper halves (orig k 400..415)
        if (tid < 256) {
            const int r = tid >> 2, c = tid & 3;
            *(f16x4*)(smem + VT_OFF + r * 848 + 768 + c * 16 + 8) = (f16x4){0, 0, 0, 0};
        }
    }
    __syncthreads();

    const float* Rbh = R + (size_t)b * NQ * DMODEL + h * 64;

    // ---------- phase 1: QKV projections ----------
    // Pass A (fused): wave wv owns Q-tile qt = qlo+wv (if wv<ntile); projects Q,K,V of that tile.
    // Pass B: leftover K/V tiles -> half0: t=9+wv (wv>=4), half1: t=wv-3 (wv>=3).
    f16x8 qreg[2];
    const int QSw = QS_OFF + wv * 2048;
    if (wv < ntile) {
        const int t = qlo + wv;
        const float* rp = Rbh + (size_t)(t * 16 + q16) * DMODEL + g * 8;
        f16x8 af0 = cvt8(rp);
        f16x8 af1 = cvt8(rp + 32);
        // Q projection -> wave-private transpose scratch -> registers
        #pragma unroll
        for (int cg = 0; cg < 4; ++cg) {
            const int col = cg * 16 + q16;
            const float bb = *(const float*)(smem + BIAS_OFF + col * 4);
            f32x4 acc = {bb, bb, bb, bb};
            f16x8 wb0 = *(const f16x8*)(smem + W_OFF + col * 128 + ((g * 16) ^ csw));
            f16x8 wb1 = *(const f16x8*)(smem + W_OFF + col * 128 + ((64 + g * 16) ^ csw));
            acc = MFMA16(af0, wb0, acc, 0, 0, 0);
            acc = MFMA16(af1, wb1, acc, 0, 0, 0);
            #pragma unroll
            for (int r = 0; r < 4; ++r) {
                const int rr = 4 * g + r;
                *(_Float16*)(smem + QSw + rr * 128 + ((col * 2) ^ ((rr & 7) << 4))) =
                    (_Float16)acc[r];
            }
        }
        proj_kv<1>(smem, af0, af1, t, g, q16, csw);
        proj_kv<2>(smem, af0, af1, t, g, q16, csw);
        asm volatile("s_waitcnt lgkmcnt(0)" ::: "memory");
        qreg[0] = *(const f16x8*)(smem + QSw + q16 * 128 + ((g * 16)      ^ csw));
        qreg[1] = *(const f16x8*)(smem + QSw + q16 * 128 + ((64 + g * 16) ^ csw));
    }
    {
        const int  t  = half ? (wv - 3) : (9 + wv);
        const bool ok = half ? (wv >= 3) : (wv >= 4);
        if (ok) {
            const float* rp = Rbh + (size_t)(t * 16 + q16) * DMODEL + g * 8;
            f16x8 af0 = cvt8(rp);
            f16x8 af1 = cvt8(rp + 32);
            proj_kv<1>(smem, af0, af1, t, g, q16, csw);
            proj_kv<2>(smem, af0, af1, t, g, q16, csw);
        }
    }
    __syncthreads();

    // ---------- phase 2: attention, P fully register-resident ----------
    if (wv < ntile) {
        unsigned mkw[13];
        #pragma unroll
        for (int i = 0; i < 13; ++i) mkw[i] = ((const unsigned*)(smem + MKB_OFF))[i];

        const int qt   = qlo + wv;
        const int qrow = qt * 16 + q16;
        const unsigned qb = (mkw[qrow >> 5] >> (qrow & 31)) & 1u;

        // swapped QK^T: lane (g,q16) accumulates S[q16][16kt+4g+r]
        f32x4 a[25];
        #pragma unroll
        for (int kt = 0; kt < 25; ++kt) {
            const int krow = kt * 16 + q16;
            f16x8 kf0 = *(const f16x8*)(smem + K_OFF + krow * 128 + ((g * 16)      ^ csw));
            f16x8 kf1 = *(const f16x8*)(smem + K_OFF + krow * 128 + ((64 + g * 16) ^ csw));
            f32x4 acc = {0.f, 0.f, 0.f, 0.f};
            acc = MFMA16(kf0, qreg[0], acc, 0, 0, 0);
            acc = MFMA16(kf1, qreg[1], acc, 0, 0, 0);
            a[kt] = acc;
        }

        // mask (bitmask penalty) + scale, row max (row is lane-local)
        float pm = -3e38f;
        #pragma unroll
        for (int kt = 0; kt < 25; ++kt) {
            const unsigned wsh = mkw[kt >> 1] >> (((kt & 1) << 4) + 4 * g);
            #pragma unroll
            for (int r = 0; r < 4; ++r) {
                float xx = a[kt][r] * SCL;
                if (!((wsh >> r) & 1u)) xx -= PEN;
                a[kt][r] = xx;
                pm = fmaxf(pm, xx);
            }
        }
        pm = fmaxf(pm, __shfl_xor(pm, 16));
        pm = fmaxf(pm, __shfl_xor(pm, 32));

        // exp2 + row sum; pack P to f16 in registers
        float ps = 0.f;
        f16x4 ph[26];
        #pragma unroll
        for (int kt = 0; kt < 25; ++kt) {
            #pragma unroll
            for (int r = 0; r < 4; ++r) {
                const float e = __builtin_amdgcn_exp2f(a[kt][r] - pm);
                ps += e;
                ph[kt][r] = (_Float16)e;
            }
        }
        ph[25] = (f16x4){0, 0, 0, 0};
        ps += __shfl_xor(ps, 16);
        ps += __shfl_xor(ps, 32);
        const float myrs = qb ? __builtin_amdgcn_rcpf(ps) : 0.0f;

        // PV: P-frag straight from registers (kappa matches permuted VT)
        f32x4 oc[4];
        #pragma unroll
        for (int cg = 0; cg < 4; ++cg) oc[cg] = (f32x4){0.f, 0.f, 0.f, 0.f};
        #pragma unroll
        for (int kc = 0; kc < 13; ++kc) {
            union { f16x4 hh[2]; f16x8 v; } pu;
            pu.hh[0] = ph[2 * kc];
            pu.hh[1] = ph[2 * kc + 1];
            const f16x8 pa = pu.v;
            #pragma unroll
            for (int cg = 0; cg < 4; ++cg) {
                f16x8 vb = *(const f16x8*)(smem + VT_OFF + (cg * 16 + q16) * 848 + kc * 64 + g * 16);
                oc[cg] = MFMA16(pa, vb, oc[cg], 0, 0, 0);
            }
        }

        // epilogue: redistribute row-scale via shfl, store fp32
        float rs[4];
        #pragma unroll
        for (int r = 0; r < 4; ++r) rs[r] = __shfl(myrs, 4 * g + r);
        float* op = out + (size_t)(b * NQ + qt * 16) * DMODEL + h * 64;
        #pragma unroll
        for (int r = 0; r < 4; ++r) {
            #pragma unroll
            for (int cg = 0; cg < 4; ++cg)
                op[(4 * g + r) * DMODEL + cg * 16 + q16] = oc[cg][r] * rs[r];
        }
    }
}

extern "C" void kernel_launch(void* const* d_in, const int* in_sizes, int n_in,
                              void* d_out, int out_size, void* d_ws, size_t ws_size,
                              hipStream_t stream) {
    const float* R    = (const float*)d_in[0];
    const float* Rmas = (const float*)d_in[1];
    const float* Wq   = (const float*)d_in[2];
    const float* bq   = (const float*)d_in[3];
    const float* Wk   = (const float*)d_in[4];
    const float* bk   = (const float*)d_in[5];
    const float* Wv   = (const float*)d_in[6];
    const float* bv   = (const float*)d_in[7];
    float* out = (float*)d_out;

    (void)hipFuncSetAttribute(reinterpret_cast<const void*>(attn_fused),
                              hipFuncAttributeMaxDynamicSharedMemorySize, SMEM_BYTES);
    attn_fused<<<dim3(768), dim3(1024), SMEM_BYTES, stream>>>(R, Rmas, Wq, bq, Wk, bk, Wv, bv, out);
}